// Round 1
// 250.727 us; speedup vs baseline: 1.0102x; 1.0102x over previous
//
#include <hip/hip_runtime.h>
#include <math.h>

// CovidModel: M[t][s] = sum_j A_full[J+t-1-j][s] * rho[s] * pi[j][s]
// A recursion replaced by closed form (removes the sequential scan):
//   A[d][s] = A0[s] * exp2(invT[s]*L[d] + (d+1)*log2(delta[s]))
//   L[d] = prefix sum of log2(r_t)  (sample-independent, in d_ws)
//
// This version vs the 253 µs DT=32 kernel:
//  - L[d] is block-uniform -> read via uniform address (scalar s_load into
//    SGPRs) instead of LDS. Kills the per-day ds_read + lgkmcnt(0) stall and
//    the __syncthreads/LDS block entirely.
//  - DT=128 as 4 *rolled* iterations (#pragma unroll 1) of the same 32-day
//    unrolled body: init (pi loads + 32 exp2) amortized 4x, code size
//    unchanged (~the old DT=128 failure was FULL unrolling thrashing I$).
//  - (d+1)*ld kept incrementally (one v_add/day).

#define T_DAYS 1024
#define J_WIN  32
#define DT     128            // days per block; 4 groups of 32
#define GROUPS (DT / 32)

// Kernel 1: L[t] = inclusive prefix sum of log2(r_t[t]); one block.
__global__ void prefix_log_kernel(const float* __restrict__ r_t,
                                  float* __restrict__ L) {
    __shared__ float buf[T_DAYS];
    const int i = threadIdx.x;
    buf[i] = __log2f(r_t[i]);
    __syncthreads();
    for (int off = 1; off < T_DAYS; off <<= 1) {
        float add = (i >= off) ? buf[i - off] : 0.0f;
        __syncthreads();
        buf[i] += add;
        __syncthreads();
    }
    L[i] = buf[i];
}

// Kernel 2: main forecast. One sample per lane, DT days per block.
__global__ __launch_bounds__(256, 4)
void covid_kernel(const float* __restrict__ warmup_A,
                  const float* __restrict__ delta_p,
                  const float* __restrict__ T_serial,
                  const float* __restrict__ rho_p,
                  const float* __restrict__ pi_M,
                  const float* __restrict__ L,
                  float* __restrict__ out,
                  int S) {
    const int s = blockIdx.x * 256 + threadIdx.x;
    if (s >= S) return;
    const int t0 = blockIdx.y * DT;   // multiple of 128

    const float invT = 1.0f / T_serial[s];
    const float dlt  = delta_p[s];
    const float ld   = __log2f(dlt);
    const float rho  = rho_p[s];
    const float A0   = warmup_A[(J_WIN - 1) * S + s];

    // Folded weights w[j] = rho * pi[j][s] (registers, compile-time indexed)
    float w[J_WIN];
#pragma unroll
    for (int j = 0; j < J_WIN; ++j) w[j] = rho * pi_M[j * S + s];

    // Ring: A(day d) lives at ring[d mod 32] (warmup day d<0 at d+32).
    // All group bases are multiples of 32, so init day t0-32+k sits at slot k.
    float ring[J_WIN];
    if (t0 == 0) {
#pragma unroll
        for (int k = 0; k < J_WIN; ++k) ring[k] = warmup_A[k * S + s];
    } else {
#pragma unroll
        for (int k = 0; k < J_WIN; ++k) {
            // L[t0-32+k] has a block-uniform address -> scalar load
            float arg = fmaf(invT, L[t0 - J_WIN + k],
                             (float)(t0 - J_WIN + k + 1) * ld);
            ring[k] = A0 * __builtin_amdgcn_exp2f(arg);
        }
    }

    float c = (float)(t0 + 1) * ld;        // (d+1)*ld for the next A-day
    float* op = out + (size_t)t0 * S + s;
    int tg = t0;
#pragma unroll 1   // keep the 32-day body rolled: code size == DT=32 version
    for (int g = 0; g < GROUPS; ++g) {
#pragma unroll
        for (int u = 0; u < 32; ++u) {
            // M[tg+u] = sum_j w[j] * A(tg+u-1-j); ring slot (u-1-j)&31 is a
            // compile-time constant after unrolling.
            float m0 = 0.0f, m1 = 0.0f, m2 = 0.0f, m3 = 0.0f;
#pragma unroll
            for (int j = 0; j < J_WIN; j += 4) {
                m0 = fmaf(w[j + 0], ring[(u - 1 - j) & 31], m0);
                m1 = fmaf(w[j + 1], ring[(u - 2 - j) & 31], m1);
                m2 = fmaf(w[j + 2], ring[(u - 3 - j) & 31], m2);
                m3 = fmaf(w[j + 3], ring[(u - 4 - j) & 31], m3);
            }
            op[(size_t)u * S] = (m0 + m1) + (m2 + m3);
            // A(tg+u) closed form; overwrites oldest slot (day tg+u-32).
            // L[tg+u] is block-uniform -> scalar load, no LDS, no barrier.
            float arg = fmaf(invT, L[tg + u], c);
            ring[u] = A0 * __builtin_amdgcn_exp2f(arg);
            c += ld;
        }
        op += (size_t)32 * S;
        tg += 32;
    }
}

extern "C" void kernel_launch(void* const* d_in, const int* in_sizes, int n_in,
                              void* d_out, int out_size, void* d_ws, size_t ws_size,
                              hipStream_t stream) {
    const float* r_t      = (const float*)d_in[0];
    const float* warmup_A = (const float*)d_in[1];
    const float* delta    = (const float*)d_in[2];
    const float* T_serial = (const float*)d_in[3];
    const float* rho_M    = (const float*)d_in[4];
    const float* pi_M     = (const float*)d_in[5];
    float* out = (float*)d_out;
    float* L   = (float*)d_ws;          // T_DAYS floats of scratch
    const int S = in_sizes[2];          // 50000

    prefix_log_kernel<<<1, T_DAYS, 0, stream>>>(r_t, L);

    dim3 grid((S + 255) / 256, T_DAYS / DT);
    covid_kernel<<<grid, 256, 0, stream>>>(warmup_A, delta, T_serial, rho_M,
                                           pi_M, L, out, S);
}